// Round 22
// baseline (103.227 us; speedup 1.0000x reference)
//
#include <hip/hip_runtime.h>
#include <hip/hip_bf16.h>

#define B_   2
#define S_   2048
#define E_   1024
#define H_   16
#define HD_  64
#define E3_  3072
#define M_   4096   // B*S
#define QKS  2048   // stride of QK buffer
#define QSC  0.1803368801111f   // 0.125 * log2(e): Q pre-scale, exp2 domain

using short8 = __attribute__((ext_vector_type(8))) short;
using f32x4  = __attribute__((ext_vector_type(4))) float;

__device__ __forceinline__ unsigned short f2bf(float f) {
  union { float f; unsigned v; } t; t.f = f;
  unsigned r = t.v + 0x7FFFu + ((t.v >> 16) & 1u);  // RNE
  return (unsigned short)(r >> 16);
}

__device__ __forceinline__ float bf2f(unsigned short u) {
  union { unsigned v; float f; } t; t.v = ((unsigned)u) << 16; return t.f;
}

__device__ __forceinline__ float exp2_fast(float x) {
  float r;
  asm("v_exp_f32 %0, %1" : "=v"(r) : "v"(x));
  return r;
}

__device__ __forceinline__ void gload16(const void* g, void* l) {
  __builtin_amdgcn_global_load_lds(
      (const __attribute__((address_space(1))) unsigned int*)g,
      (__attribute__((address_space(3))) unsigned int*)l, 16, 0, 0);
}

// ---- prep: X f32->bf16 + both weight transposes, one launch ----
// blocks [0,4096): cvt X; [4096,7168): transpose Wa; [7168,8192): transpose Wp
__global__ __launch_bounds__(256) void prep(
    const float* __restrict__ X, const float* __restrict__ Wa,
    const float* __restrict__ Wp,
    unsigned short* __restrict__ Xb, unsigned short* __restrict__ WaT,
    unsigned short* __restrict__ WpT) {
  __shared__ float tile[32][33];
  const int id = blockIdx.x;
  if (id < 4096) {
    const int i = (id * 256 + threadIdx.x) * 4;
    float4 v = *(const float4*)(X + i);
    ushort4 o;
    o.x = f2bf(v.x); o.y = f2bf(v.y); o.z = f2bf(v.z); o.w = f2bf(v.w);
    *(ushort4*)(Xb + i) = o;
  } else {
    const float* W; unsigned short* WT; int N, bn, bk;
    if (id < 7168) {
      W = Wa; WT = WaT; N = E3_;
      const int j = id - 4096; bn = (j % 96) * 32; bk = (j / 96) * 32;
    } else {
      W = Wp; WT = WpT; N = E_;
      const int j = id - 7168; bn = (j & 31) * 32; bk = (j >> 5) * 32;
    }
    const int tx = threadIdx.x & 31, ty = threadIdx.x >> 5;  // 32 x 8
    #pragma unroll
    for (int i2 = 0; i2 < 32; i2 += 8)
      tile[ty + i2][tx] = W[(size_t)(bk + ty + i2) * N + bn + tx];
    __syncthreads();
    #pragma unroll
    for (int i2 = 0; i2 < 32; i2 += 8)
      WT[(size_t)(bn + ty + i2) * E_ + bk + tx] = f2bf(tile[tx][ty + i2]);
  }
}

// ------- 128x128 bf16 MFMA GEMM, BK=64, XOR-swizzled LDS, fused bias -------
// Runtime M,N,K keeps the K-loop ROLLED (compile-time K fully unrolls and
// thrashes I$ -- the R17 regression).
// MODE 0: f32 out, ldc = N.
// MODE 1: qkv split -> Q cols (<1024) pre-scaled by QSC, bf16 into Cbf;
//         K cols (1024..2047) bf16 into Cbf; V cols (>=2048) transposed
//         into Vt[bh][d][s].
template <int MODE>
__global__ __launch_bounds__(256) void gemm_bt_bias(
    const unsigned short* __restrict__ A,
    const unsigned short* __restrict__ BT,
    const float* __restrict__ bias,
    float* __restrict__ Cf,
    unsigned short* __restrict__ Cbf,
    unsigned short* __restrict__ Vt,
    int M, int N, int K) {
  __shared__ __align__(16) unsigned short As[128 * 64];
  __shared__ __align__(16) unsigned short Bs[128 * 64];
  const int t = threadIdx.x;
  const int lane = t & 63, w = t >> 6;
  const int wr = w >> 1, wc = w & 1;
  const int m0 = blockIdx.y * 128, n0 = blockIdx.x * 128;
  const int lrow = lane & 15, lkg = lane >> 4;   // frag row / k-granule
  const int srow = t >> 3;            // 0..31 (+32p)
  const int sc8  = (t & 7) * 8;       // granule base (elems)
  const int sgc  = sc8 ^ (((t >> 3) & 7) << 3);  // swizzled source col

  f32x4 acc[4][4];
  const f32x4 z = {0.f, 0.f, 0.f, 0.f};
  #pragma unroll
  for (int i = 0; i < 4; ++i)
    #pragma unroll
    for (int j = 0; j < 4; ++j) acc[i][j] = z;

  for (int k0 = 0; k0 < K; k0 += 64) {
    __syncthreads();
    #pragma unroll
    for (int p = 0; p < 4; ++p) {
      const int r = srow + 32 * p;
      gload16(A  + (size_t)(m0 + r) * K + k0 + sgc, &As[r * 64 + sc8]);
      gload16(BT + (size_t)(n0 + r) * K + k0 + sgc, &Bs[r * 64 + sc8]);
    }
    __syncthreads();

    short8 af[4][2], bf[4][2];
    #pragma unroll
    for (int m = 0; m < 4; ++m) {
      const int row = wr * 64 + m * 16 + lrow;
      const int base = row * 64, sw = (row & 7) << 3;
      af[m][0] = *(const short8*)&As[base + ((lkg * 8) ^ sw)];
      af[m][1] = *(const short8*)&As[base + ((32 + lkg * 8) ^ sw)];
    }
    #pragma unroll
    for (int n = 0; n < 4; ++n) {
      const int row = wc * 64 + n * 16 + lrow;
      const int base = row * 64, sw = (row & 7) << 3;
      bf[n][0] = *(const short8*)&Bs[base + ((lkg * 8) ^ sw)];
      bf[n][1] = *(const short8*)&Bs[base + ((32 + lkg * 8) ^ sw)];
    }
    #pragma unroll
    for (int m = 0; m < 4; ++m)
      #pragma unroll
      for (int n = 0; n < 4; ++n) {
        acc[m][n] = __builtin_amdgcn_mfma_f32_16x16x32_bf16(af[m][0], bf[n][0],
                                                            acc[m][n], 0, 0, 0);
        acc[m][n] = __builtin_amdgcn_mfma_f32_16x16x32_bf16(af[m][1], bf[n][1],
                                                            acc[m][n], 0, 0, 0);
      }
  }

  const int r0 = (lane >> 4) * 4, c0 = lane & 15;
  #pragma unroll
  for (int m = 0; m < 4; ++m) {
    #pragma unroll
    for (int n = 0; n < 4; ++n) {
      const int row = m0 + wr * 64 + m * 16 + r0;
      const int col = n0 + wc * 64 + n * 16 + c0;
      const float bv = bias[col];
      if (MODE == 0) {
        #pragma unroll
        for (int r = 0; r < 4; ++r)
          Cf[(size_t)(row + r) * N + col] = acc[m][n][r] + bv;
      } else {
        if (col < 2 * E_) {
          const float sc = (col < E_) ? QSC : 1.0f;  // uniform per 16-col block
          #pragma unroll
          for (int r = 0; r < 4; ++r)
            Cbf[(size_t)(row + r) * QKS + col] = f2bf((acc[m][n][r] + bv) * sc);
        } else {
          const int hd = col - 2 * E_;
          ushort4 o;
          o.x = f2bf(acc[m][n][0] + bv);
          o.y = f2bf(acc[m][n][1] + bv);
          o.z = f2bf(acc[m][n][2] + bv);
          o.w = f2bf(acc[m][n][3] + bv);
          *(ushort4*)&Vt[(((size_t)(row >> 11) * H_ + (hd >> 6)) * HD_ +
                          (hd & 63)) * (size_t)S_ + (row & 2047)] = o;
        }
      }
    }
  }
}

// keep MODE=0 instantiated so the module's codegen context stays stable
template __global__ void gemm_bt_bias<0>(
    const unsigned short*, const unsigned short*, const float*, float*,
    unsigned short*, unsigned short*, int, int, int);

// ------- proj GEMM: 128x64 tile (512 blocks = 2/CU), BK=64, swizzled -------
// Wave grid 2M x 2N; per-wave 64x32 output. f32 out. Runtime dims (rolled).
__global__ __launch_bounds__(256) void gemm_proj(
    const unsigned short* __restrict__ A,
    const unsigned short* __restrict__ BT,
    const float* __restrict__ bias,
    float* __restrict__ Cf, int M, int N, int K) {
  __shared__ __align__(16) unsigned short As[128 * 64];
  __shared__ __align__(16) unsigned short Bs[64 * 64];
  const int t = threadIdx.x;
  const int lane = t & 63, w = t >> 6;
  const int wr = w >> 1, wc = w & 1;        // 2M x 2N
  const int m0 = blockIdx.y * 128, n0 = blockIdx.x * 64;
  const int lrow = lane & 15, lkg = lane >> 4;
  const int srow = t >> 3;            // 0..31 (+32p)
  const int sc8  = (t & 7) * 8;
  const int sgc  = sc8 ^ (((t >> 3) & 7) << 3);

  f32x4 acc[4][2];
  const f32x4 z = {0.f, 0.f, 0.f, 0.f};
  #pragma unroll
  for (int i = 0; i < 4; ++i) { acc[i][0] = z; acc[i][1] = z; }

  for (int k0 = 0; k0 < K; k0 += 64) {
    __syncthreads();
    #pragma unroll
    for (int p = 0; p < 4; ++p) {
      const int r = srow + 32 * p;
      gload16(A + (size_t)(m0 + r) * K + k0 + sgc, &As[r * 64 + sc8]);
    }
    #pragma unroll
    for (int p = 0; p < 2; ++p) {
      const int r = srow + 32 * p;
      gload16(BT + (size_t)(n0 + r) * K + k0 + sgc, &Bs[r * 64 + sc8]);
    }
    __syncthreads();

    short8 af[4][2], bf[2][2];
    #pragma unroll
    for (int m = 0; m < 4; ++m) {
      const int row = wr * 64 + m * 16 + lrow;
      const int base = row * 64, sw = (row & 7) << 3;
      af[m][0] = *(const short8*)&As[base + ((lkg * 8) ^ sw)];
      af[m][1] = *(const short8*)&As[base + ((32 + lkg * 8) ^ sw)];
    }
    #pragma unroll
    for (int n = 0; n < 2; ++n) {
      const int row = wc * 32 + n * 16 + lrow;
      const int base = row * 64, sw = (row & 7) << 3;
      bf[n][0] = *(const short8*)&Bs[base + ((lkg * 8) ^ sw)];
      bf[n][1] = *(const short8*)&Bs[base + ((32 + lkg * 8) ^ sw)];
    }
    #pragma unroll
    for (int m = 0; m < 4; ++m)
      #pragma unroll
      for (int n = 0; n < 2; ++n) {
        acc[m][n] = __builtin_amdgcn_mfma_f32_16x16x32_bf16(af[m][0], bf[n][0],
                                                            acc[m][n], 0, 0, 0);
        acc[m][n] = __builtin_amdgcn_mfma_f32_16x16x32_bf16(af[m][1], bf[n][1],
                                                            acc[m][n], 0, 0, 0);
      }
  }

  const int r0 = (lane >> 4) * 4, c0 = lane & 15;
  #pragma unroll
  for (int m = 0; m < 4; ++m) {
    #pragma unroll
    for (int n = 0; n < 2; ++n) {
      const int row = m0 + wr * 64 + m * 16 + r0;
      const int col = n0 + wc * 32 + n * 16 + c0;
      const float bv = bias[col];
      #pragma unroll
      for (int r = 0; r < 4; ++r)
        Cf[(size_t)(row + r) * N + col] = acc[m][n][r] + bv;
    }
  }
}

// ---- flash attention (causal), QBLK=128, 4 waves x 32 q (2 chunks) ----
// Swapped-QK^T; exp2-domain scores; fixed-reference softmax; l via ones-MFMA.
// KEY: K/V fragment LDS addresses are wave-invariant, so each wave reads the
// kf/vb fragments ONCE and feeds TWO 16-q chunks -> per-CU LDS-read traffic
// halved vs the 8-wave version (which was LDS-port bound).
// Triple-buffered K/V (48 KB -> 3 blocks/CU = grid capacity 768), prefetch
// depth 2 with counted s_waitcnt vmcnt(4). qt128 blocks 8..15 split into two
// kv-chunks (bf16 partials + attn_combine); 0..7 whole. Grid (32,24).
__global__ __launch_bounds__(256) void flash_attn(
    const unsigned short* __restrict__ qk,
    const unsigned short* __restrict__ Vt,
    unsigned short* __restrict__ aout,
    unsigned short* __restrict__ Opart,  // [256][2][128][64] bf16
    float* __restrict__ Lpart) {         // [256][2][128]
  __shared__ __align__(16) unsigned short Ks[3][64 * 64];   // [k][d], swizzled
  __shared__ __align__(16) unsigned short Vs[3][64 * 64];   // [d][k], swizzled

  const int t = threadIdx.x, lane = t & 63, w = t >> 6;     // w: 0..3
  const int bh = blockIdx.x;
  const int yy = blockIdx.y;            // 0..23
  int qt, lo, hi, part = 0;
  bool split = false;
  if (yy < 8) {                         // whole blocks: qt 0..7
    qt = yy; lo = 0; hi = 2 * qt + 2;
  } else if (yy < 16) {                 // chunk part0 of qt 15..8
    qt = 15 - (yy - 8); part = 0; split = true;
    lo = 0; hi = qt + 1;
  } else {                              // chunk part1 of qt 15..8 (has diag)
    qt = 15 - (yy - 16); part = 1; split = true;
    lo = qt + 1; hi = 2 * qt + 2;
  }
  const int b = bh >> 4, h = bh & 15;
  const int lq = lane & 15;
  const int g  = lane >> 4;
  const int lk8 = g * 8;
  const int swzq = (lq & 7) << 3;
  const size_t basebs = (size_t)b * S_;
  const f32x4 z = {0.f, 0.f, 0.f, 0.f};
  const short8 ones = {(short)0x3F80, (short)0x3F80, (short)0x3F80,
                       (short)0x3F80, (short)0x3F80, (short)0x3F80,
                       (short)0x3F80, (short)0x3F80};   // bf16 1.0 x8

  // Q fragments: wave w, chunk c owns q-rows qt*128 + c*64 + w*16 + [0,16)
  short8 qf[2][2];
  #pragma unroll
  for (int c = 0; c < 2; ++c) {
    const int qrow = qt * 128 + c * 64 + w * 16 + lq;
    const unsigned short* qp = qk + (basebs + qrow) * QKS + h * HD_;
    qf[c][0] = *(const short8*)(qp + lk8);
    qf[c][1] = *(const short8*)(qp + 32 + lk8);
  }

  f32x4 l_acc[2] = {z, z};              // l_acc[c][r] = l[q = c*64+w*16+4g+r]
  f32x4 o_acc[2][4];
  #pragma unroll
  for (int c = 0; c < 2; ++c)
    #pragma unroll
    for (int n = 0; n < 4; ++n) o_acc[c][n] = z;

  // staging (R13-proven 256-thread pattern): 4 gload16/thread per tile
  const int sr = t >> 3;                // 0..31 (+32)
  const int scc = (t & 7) * 8;
  const unsigned short* kp0 =
      qk + (basebs + sr) * QKS + E_ + h * HD_ + (scc ^ ((sr & 7) << 3));
  const unsigned short* kp1 = kp0 + 32 * QKS;
  const unsigned short* vp0 =
      Vt + ((size_t)bh * HD_ + sr) * S_ + (scc ^ ((sr & 7) << 3));
  const unsigned short* vp1 = vp0 + 32 * S_;

  auto stage = [&](int kt) {            // tile kt -> buffer kt%3 (4 loads)
    const int buf = kt % 3;
    const size_t koff = (size_t)kt * 64 * QKS;
    const size_t voff = (size_t)kt * 64;
    gload16(kp0 + koff, &Ks[buf][t * 8]);
    gload16(kp1 + koff, &Ks[buf][t * 8 + 2048]);
    gload16(vp0 + voff, &Vs[buf][t * 8]);
    gload16(vp1 + voff, &Vs[buf][t * 8 + 2048]);
  };

  stage(lo);
  if (lo + 1 < hi) stage(lo + 1);

  for (int kt = lo; kt < hi; ++kt) {
    // counted wait: tile kt's 4 loads done; tile kt+1's 4 may stay in flight
    if (kt < hi - 1) {
      asm volatile("s_waitcnt vmcnt(4)" ::: "memory");
    } else {
      asm volatile("s_waitcnt vmcnt(0)" ::: "memory");
    }
    __builtin_amdgcn_sched_barrier(0);
    __builtin_amdgcn_s_barrier();
    __builtin_amdgcn_sched_barrier(0);

    if (kt + 2 < hi) stage(kt + 2);

    const int cur = kt % 3;
    const int krel = kt - 2 * qt;       // 0/1 on diagonal tiles, else <0

    // K fragments read ONCE, shared by both chunks
    short8 kf[4][2];
    #pragma unroll
    for (int f = 0; f < 4; ++f) {
      const int rowb = (f * 16 + lq) * 64;
      kf[f][0] = *(const short8*)&Ks[cur][rowb + (lk8 ^ swzq)];
      kf[f][1] = *(const short8*)&Ks[cur][rowb + ((lk8 + 32) ^ swzq)];
    }

    short8 pa[2][2];
    #pragma unroll
    for (int c = 0; c < 2; ++c) {
      if (krel == 1 && c == 0) continue;     // chunk fully masked
      f32x4 st[4];
      __builtin_amdgcn_s_setprio(1);
      #pragma unroll
      for (int f = 0; f < 4; ++f) {
        st[f] = __builtin_amdgcn_mfma_f32_16x16x32_bf16(kf[f][0], qf[c][0], z, 0, 0, 0);
        st[f] = __builtin_amdgcn_mfma_f32_16x16x32_bf16(kf[f][1], qf[c][1], st[f], 0, 0, 0);
      }
      __builtin_amdgcn_s_setprio(0);

      if (krel == c) {                  // diagonal for this chunk
        const int qcol = w * 16 + lq;
        #pragma unroll
        for (int f = 0; f < 4; ++f)
          #pragma unroll
          for (int r = 0; r < 4; ++r)
            if (16 * f + 4 * g + r > qcol) st[f][r] = -1e30f;
      }

      unsigned pw[4][2];
      #pragma unroll
      for (int f = 0; f < 4; ++f) {
        float p0 = exp2_fast(st[f][0]);
        float p1 = exp2_fast(st[f][1]);
        float p2 = exp2_fast(st[f][2]);
        float p3 = exp2_fast(st[f][3]);
        asm("v_cvt_pk_bf16_f32 %0, %1, %2" : "=v"(pw[f][0]) : "v"(p0), "v"(p1));
        asm("v_cvt_pk_bf16_f32 %0, %1, %2" : "=v"(pw[f][1]) : "v"(p2), "v"(p3));
      }

      unsigned c1a = pw[0][0], c1b = pw[1][0];
      unsigned c2a = pw[0][1], c2b = pw[1][1];
      unsigned c3a = pw[2][0], c3b = pw[3][0];
      unsigned c4a = pw[2][1], c4b = pw[3][1];
      asm("v_permlane32_swap_b32 %0, %1" : "+v"(c1a), "+v"(c1b));
      asm("v_permlane16_swap_b32 %0, %1" : "+v"(c1a), "+v"(c1b));
      asm("v_permlane32_swap_b32 %0, %1" : "+v"(c2a), "+v"(c2b));
      asm("v_permlane16_swap_b32 %0, %1" : "+v"(c2a), "+v"(c2b));
      asm("v_permlane32_swap_b32 %0, %1" : "+v"(c3a), "+v"(c3b));
      asm("v_permlane16_swap_b32 %0, %1" : "+v"(c3a), "+v"(c3b));
      asm("v_permlane32_swap_b32 %0, %1" : "+v"(c4a), "+v"(c4b));
      asm("v_permlane16_swap_b32 %0, %1" : "+v"(c4a), "+v"(c4b));
      union U8 { unsigned u[4]; short8 s; };
      U8 pa0u = {{c1a, c2a, c1b, c2b}};
      U8 pa1u = {{c3a, c4a, c3b, c4b}};
      pa[c][0] = pa0u.s;
      pa[c][1] = pa1u.s;
    }

    // V fragments read ONCE (reuse kf registers), shared by both chunks
    #pragma unroll
    for (int f = 0; f < 4; ++f) {
      const int rowb = (f * 16 + lq) * 64;
      kf[f][0] = *(const short8*)&Vs[cur][rowb + (lk8 ^ swzq)];
      kf[f][1] = *(const short8*)&Vs[cur][rowb + ((lk8 + 32) ^ swzq)];
    }
    __builtin_amdgcn_s_setprio(1);
    #pragma unroll
    for (int c = 0; c < 2; ++c) {
      if (krel == 1 && c == 0) continue;
      #pragma unroll
      for (int n = 0; n < 4; ++n) {
        o_acc[c][n] = __builtin_amdgcn_mfma_f32_16x16x32_bf16(pa[c][0], kf[n][0],
                                                              o_acc[c][n], 0, 0, 0);
        o_acc[c][n] = __builtin_amdgcn_mfma_f32_16x16x32_bf16(pa[c][1], kf[n][1],
                                                              o_acc[c][n], 0, 0, 0);
      }
      l_acc[c] = __builtin_amdgcn_mfma_f32_16x16x32_bf16(pa[c][0], ones,
                                                         l_acc[c], 0, 0, 0);
      l_acc[c] = __builtin_amdgcn_mfma_f32_16x16x32_bf16(pa[c][1], ones,
                                                         l_acc[c], 0, 0, 0);
    }
    __builtin_amdgcn_s_setprio(0);
    __builtin_amdgcn_sched_barrier(0);  // keep compute inside its step
  }

  if (!split) {
    #pragma unroll
    for (int c = 0; c < 2; ++c) {
      const int qbase = qt * 128 + c * 64 + w * 16 + 4 * g;
      #pragma unroll
      for (int r = 0; r < 4; ++r) {
        const float inv = 1.0f / l_acc[c][r];
        const int row = qbase + r;
        #pragma unroll
        for (int n = 0; n < 4; ++n)
          aout[(basebs + row) * E_ + h * HD_ + n * 16 + lq] =
              f2bf(o_acc[c][n][r] * inv);
      }
    }
  } else {
    // bf16 unnormalized partials; slot owned exclusively by this chunk
    const int sidx = (bh << 3) | (qt - 8);
    unsigned short* Ob = Opart + ((size_t)(sidx * 2 + part) << 13);  // 128*64
    #pragma unroll
    for (int c = 0; c < 2; ++c) {
      #pragma unroll
      for (int r = 0; r < 4; ++r) {
        const int qrow = c * 64 + w * 16 + 4 * g + r;
        #pragma unroll
        for (int n = 0; n < 4; ++n)
          Ob[qrow * 64 + n * 16 + lq] = f2bf(o_acc[c][n][r]);
      }
      if (lq == 0) {
        #pragma unroll
        for (int r = 0; r < 4; ++r)
          Lpart[(sidx * 2 + part) * 128 + c * 64 + w * 16 + 4 * g + r] =
              l_acc[c][r];
      }
    }
  }
}

// ---------------- combine partials for split row-blocks ----------------
__global__ __launch_bounds__(256) void attn_combine(
    const unsigned short* __restrict__ Opart, const float* __restrict__ Lpart,
    unsigned short* __restrict__ aout) {
  const int s = blockIdx.x;            // 0..255
  const int bh = s >> 3, qtb = 8 + (s & 7);
  const int b = bh >> 4, h = bh & 15;
  const int t = threadIdx.x;
  const int q = t >> 1;                // 0..127
  const int d0 = (t & 1) * 32;
  const float l = Lpart[(s * 2 + 0) * 128 + q] + Lpart[(s * 2 + 1) * 128 + q];
  const float inv = 1.0f / l;
  const unsigned short* p0 = Opart + ((size_t)(s * 2 + 0) << 13) + q * 64 + d0;
  const unsigned short* p1 = Opart + ((size_t)(s * 2 + 1) << 13) + q * 64 + d0;
  unsigned short* dst =
      aout + ((size_t)b * S_ + qtb * 128 + q) * E_ + h * HD_ + d0;
  #pragma unroll
  for (int i = 0; i < 32; ++i)
    dst[i] = f2bf((bf2f(p0[i]) + bf2f(p1[i])) * inv);
}

extern "C" void kernel_launch(void* const* d_in, const int* in_sizes, int n_in,
                              void* d_out, int out_size, void* d_ws, size_t ws_size,
                              hipStream_t stream) {
  const float* X  = (const float*)d_in[0];
  const float* Wa = (const float*)d_in[1];
  const float* ba = (const float*)d_in[2];
  const float* Wp = (const float*)d_in[3];
  const float* bp = (const float*)d_in[4];
  float* out = (float*)d_out;

  char* ws = (char*)d_ws;
  unsigned short* Xb  = (unsigned short*)ws; ws += (size_t)M_ * E_ * 2;    // 8 MB
  unsigned short* WaT = (unsigned short*)ws; ws += (size_t)E3_ * E_ * 2;   // 6 MB
  unsigned short* WpT = (unsigned short*)ws; ws += (size_t)E_ * E_ * 2;    // 2 MB
  unsigned short* QK  = (unsigned short*)ws; ws += (size_t)M_ * QKS * 2;   // 16 MB
  unsigned short* Vt  = (unsigned short*)ws; ws += (size_t)M_ * E_ * 2;    // 8 MB
  unsigned short* AO  = (unsigned short*)ws; ws += (size_t)M_ * E_ * 2;    // 8 MB
  unsigned short* Opart = (unsigned short*)ws;
  ws += (size_t)256 * 2 * 128 * 64 * 2;                                    // 8.4 MB
  float* Lpart = (float*)ws; ws += (size_t)256 * 2 * 128 * 4;              // 256 KB

  prep<<<8192, 256, 0, stream>>>(X, Wa, Wp, Xb, WaT, WpT);
  gemm_bt_bias<1><<<dim3(E3_ / 128, M_ / 128), 256, 0, stream>>>(
      Xb, WaT, ba, nullptr, QK, Vt, M_, E3_, E_);
  flash_attn<<<dim3(B_ * H_, 24), 256, 0, stream>>>(QK, Vt, AO, Opart, Lpart);
  attn_combine<<<256, 256, 0, stream>>>(Opart, Lpart, AO);
  gemm_proj<<<dim3(E_ / 64, M_ / 128), 256, 0, stream>>>(
      AO, WpT, bp, out, M_, E_, E_);
}

// Round 23
// 96.666 us; speedup vs baseline: 1.0679x; 1.0679x over previous
//
#include <hip/hip_runtime.h>
#include <hip/hip_bf16.h>

#define B_   2
#define S_   2048
#define E_   1024
#define H_   16
#define HD_  64
#define E3_  3072
#define M_   4096   // B*S
#define QKS  2048   // stride of QK buffer
#define QSC  0.1803368801111f   // 0.125 * log2(e): Q pre-scale, exp2 domain

using short8 = __attribute__((ext_vector_type(8))) short;
using f32x4  = __attribute__((ext_vector_type(4))) float;

__device__ __forceinline__ unsigned short f2bf(float f) {
  union { float f; unsigned v; } t; t.f = f;
  unsigned r = t.v + 0x7FFFu + ((t.v >> 16) & 1u);  // RNE
  return (unsigned short)(r >> 16);
}

__device__ __forceinline__ float bf2f(unsigned short u) {
  union { unsigned v; float f; } t; t.v = ((unsigned)u) << 16; return t.f;
}

__device__ __forceinline__ float exp2_fast(float x) {
  float r;
  asm("v_exp_f32 %0, %1" : "=v"(r) : "v"(x));
  return r;
}

__device__ __forceinline__ void gload16(const void* g, void* l) {
  __builtin_amdgcn_global_load_lds(
      (const __attribute__((address_space(1))) unsigned int*)g,
      (__attribute__((address_space(3))) unsigned int*)l, 16, 0, 0);
}

// ---- prep: X f32->bf16 + both weight transposes, one launch ----
// blocks [0,4096): cvt X; [4096,7168): transpose Wa; [7168,8192): transpose Wp
__global__ __launch_bounds__(256) void prep(
    const float* __restrict__ X, const float* __restrict__ Wa,
    const float* __restrict__ Wp,
    unsigned short* __restrict__ Xb, unsigned short* __restrict__ WaT,
    unsigned short* __restrict__ WpT) {
  __shared__ float tile[32][33];
  const int id = blockIdx.x;
  if (id < 4096) {
    const int i = (id * 256 + threadIdx.x) * 4;
    float4 v = *(const float4*)(X + i);
    ushort4 o;
    o.x = f2bf(v.x); o.y = f2bf(v.y); o.z = f2bf(v.z); o.w = f2bf(v.w);
    *(ushort4*)(Xb + i) = o;
  } else {
    const float* W; unsigned short* WT; int N, bn, bk;
    if (id < 7168) {
      W = Wa; WT = WaT; N = E3_;
      const int j = id - 4096; bn = (j % 96) * 32; bk = (j / 96) * 32;
    } else {
      W = Wp; WT = WpT; N = E_;
      const int j = id - 7168; bn = (j & 31) * 32; bk = (j >> 5) * 32;
    }
    const int tx = threadIdx.x & 31, ty = threadIdx.x >> 5;  // 32 x 8
    #pragma unroll
    for (int i2 = 0; i2 < 32; i2 += 8)
      tile[ty + i2][tx] = W[(size_t)(bk + ty + i2) * N + bn + tx];
    __syncthreads();
    #pragma unroll
    for (int i2 = 0; i2 < 32; i2 += 8)
      WT[(size_t)(bn + ty + i2) * E_ + bk + tx] = f2bf(tile[tx][ty + i2]);
  }
}

// ------- 128x128 bf16 MFMA GEMM, BK=64, XOR-swizzled LDS, fused bias -------
// Runtime M,N,K keeps the K-loop ROLLED (compile-time K fully unrolls ~1000
// instrs and thrashes I$ -- the R17 regression).
// MODE 0: f32 out, ldc = N.
// MODE 1: qkv split -> Q cols (<1024) pre-scaled by QSC, bf16 into Cbf;
//         K cols (1024..2047) bf16 into Cbf; V cols (>=2048) transposed
//         into Vt[bh][d][s].
template <int MODE>
__global__ __launch_bounds__(256) void gemm_bt_bias(
    const unsigned short* __restrict__ A,
    const unsigned short* __restrict__ BT,
    const float* __restrict__ bias,
    float* __restrict__ Cf,
    unsigned short* __restrict__ Cbf,
    unsigned short* __restrict__ Vt,
    int M, int N, int K) {
  __shared__ __align__(16) unsigned short As[128 * 64];
  __shared__ __align__(16) unsigned short Bs[128 * 64];
  const int t = threadIdx.x;
  const int lane = t & 63, w = t >> 6;
  const int wr = w >> 1, wc = w & 1;
  const int m0 = blockIdx.y * 128, n0 = blockIdx.x * 128;
  const int lrow = lane & 15, lkg = lane >> 4;   // frag row / k-granule
  const int srow = t >> 3;            // 0..31 (+32p)
  const int sc8  = (t & 7) * 8;       // granule base (elems)
  const int sgc  = sc8 ^ (((t >> 3) & 7) << 3);  // swizzled source col

  f32x4 acc[4][4];
  const f32x4 z = {0.f, 0.f, 0.f, 0.f};
  #pragma unroll
  for (int i = 0; i < 4; ++i)
    #pragma unroll
    for (int j = 0; j < 4; ++j) acc[i][j] = z;

  for (int k0 = 0; k0 < K; k0 += 64) {
    __syncthreads();
    #pragma unroll
    for (int p = 0; p < 4; ++p) {
      const int r = srow + 32 * p;
      gload16(A  + (size_t)(m0 + r) * K + k0 + sgc, &As[r * 64 + sc8]);
      gload16(BT + (size_t)(n0 + r) * K + k0 + sgc, &Bs[r * 64 + sc8]);
    }
    __syncthreads();

    short8 af[4][2], bf[4][2];
    #pragma unroll
    for (int m = 0; m < 4; ++m) {
      const int row = wr * 64 + m * 16 + lrow;
      const int base = row * 64, sw = (row & 7) << 3;
      af[m][0] = *(const short8*)&As[base + ((lkg * 8) ^ sw)];
      af[m][1] = *(const short8*)&As[base + ((32 + lkg * 8) ^ sw)];
    }
    #pragma unroll
    for (int n = 0; n < 4; ++n) {
      const int row = wc * 64 + n * 16 + lrow;
      const int base = row * 64, sw = (row & 7) << 3;
      bf[n][0] = *(const short8*)&Bs[base + ((lkg * 8) ^ sw)];
      bf[n][1] = *(const short8*)&Bs[base + ((32 + lkg * 8) ^ sw)];
    }
    #pragma unroll
    for (int m = 0; m < 4; ++m)
      #pragma unroll
      for (int n = 0; n < 4; ++n) {
        acc[m][n] = __builtin_amdgcn_mfma_f32_16x16x32_bf16(af[m][0], bf[n][0],
                                                            acc[m][n], 0, 0, 0);
        acc[m][n] = __builtin_amdgcn_mfma_f32_16x16x32_bf16(af[m][1], bf[n][1],
                                                            acc[m][n], 0, 0, 0);
      }
  }

  const int r0 = (lane >> 4) * 4, c0 = lane & 15;
  #pragma unroll
  for (int m = 0; m < 4; ++m) {
    #pragma unroll
    for (int n = 0; n < 4; ++n) {
      const int row = m0 + wr * 64 + m * 16 + r0;
      const int col = n0 + wc * 64 + n * 16 + c0;
      const float bv = bias[col];
      if (MODE == 0) {
        #pragma unroll
        for (int r = 0; r < 4; ++r)
          Cf[(size_t)(row + r) * N + col] = acc[m][n][r] + bv;
      } else {
        if (col < 2 * E_) {
          const float sc = (col < E_) ? QSC : 1.0f;  // uniform per 16-col block
          #pragma unroll
          for (int r = 0; r < 4; ++r)
            Cbf[(size_t)(row + r) * QKS + col] = f2bf((acc[m][n][r] + bv) * sc);
        } else {
          const int hd = col - 2 * E_;
          ushort4 o;
          o.x = f2bf(acc[m][n][0] + bv);
          o.y = f2bf(acc[m][n][1] + bv);
          o.z = f2bf(acc[m][n][2] + bv);
          o.w = f2bf(acc[m][n][3] + bv);
          *(ushort4*)&Vt[(((size_t)(row >> 11) * H_ + (hd >> 6)) * HD_ +
                          (hd & 63)) * (size_t)S_ + (row & 2047)] = o;
        }
      }
    }
  }
}

// keep MODE=0 instantiated so the module's codegen context matches R16
template __global__ void gemm_bt_bias<0>(
    const unsigned short*, const unsigned short*, const float*, float*,
    unsigned short*, unsigned short*, int, int, int);

// ------- proj GEMM: 128x64 tile (512 blocks = 2/CU), BK=64, swizzled -------
// Wave grid 2M x 2N; per-wave 64x32 output. f32 out. Runtime dims (rolled).
__global__ __launch_bounds__(256) void gemm_proj(
    const unsigned short* __restrict__ A,
    const unsigned short* __restrict__ BT,
    const float* __restrict__ bias,
    float* __restrict__ Cf, int M, int N, int K) {
  __shared__ __align__(16) unsigned short As[128 * 64];
  __shared__ __align__(16) unsigned short Bs[64 * 64];
  const int t = threadIdx.x;
  const int lane = t & 63, w = t >> 6;
  const int wr = w >> 1, wc = w & 1;        // 2M x 2N
  const int m0 = blockIdx.y * 128, n0 = blockIdx.x * 64;
  const int lrow = lane & 15, lkg = lane >> 4;
  const int srow = t >> 3;            // 0..31 (+32p)
  const int sc8  = (t & 7) * 8;
  const int sgc  = sc8 ^ (((t >> 3) & 7) << 3);

  f32x4 acc[4][2];
  const f32x4 z = {0.f, 0.f, 0.f, 0.f};
  #pragma unroll
  for (int i = 0; i < 4; ++i) { acc[i][0] = z; acc[i][1] = z; }

  for (int k0 = 0; k0 < K; k0 += 64) {
    __syncthreads();
    #pragma unroll
    for (int p = 0; p < 4; ++p) {
      const int r = srow + 32 * p;
      gload16(A + (size_t)(m0 + r) * K + k0 + sgc, &As[r * 64 + sc8]);
    }
    #pragma unroll
    for (int p = 0; p < 2; ++p) {
      const int r = srow + 32 * p;
      gload16(BT + (size_t)(n0 + r) * K + k0 + sgc, &Bs[r * 64 + sc8]);
    }
    __syncthreads();

    short8 af[4][2], bf[2][2];
    #pragma unroll
    for (int m = 0; m < 4; ++m) {
      const int row = wr * 64 + m * 16 + lrow;
      const int base = row * 64, sw = (row & 7) << 3;
      af[m][0] = *(const short8*)&As[base + ((lkg * 8) ^ sw)];
      af[m][1] = *(const short8*)&As[base + ((32 + lkg * 8) ^ sw)];
    }
    #pragma unroll
    for (int n = 0; n < 2; ++n) {
      const int row = wc * 32 + n * 16 + lrow;
      const int base = row * 64, sw = (row & 7) << 3;
      bf[n][0] = *(const short8*)&Bs[base + ((lkg * 8) ^ sw)];
      bf[n][1] = *(const short8*)&Bs[base + ((32 + lkg * 8) ^ sw)];
    }
    #pragma unroll
    for (int m = 0; m < 4; ++m)
      #pragma unroll
      for (int n = 0; n < 2; ++n) {
        acc[m][n] = __builtin_amdgcn_mfma_f32_16x16x32_bf16(af[m][0], bf[n][0],
                                                            acc[m][n], 0, 0, 0);
        acc[m][n] = __builtin_amdgcn_mfma_f32_16x16x32_bf16(af[m][1], bf[n][1],
                                                            acc[m][n], 0, 0, 0);
      }
  }

  const int r0 = (lane >> 4) * 4, c0 = lane & 15;
  #pragma unroll
  for (int m = 0; m < 4; ++m) {
    #pragma unroll
    for (int n = 0; n < 2; ++n) {
      const int row = m0 + wr * 64 + m * 16 + r0;
      const int col = n0 + wc * 32 + n * 16 + c0;
      const float bv = bias[col];
      #pragma unroll
      for (int r = 0; r < 4; ++r)
        Cf[(size_t)(row + r) * N + col] = acc[m][n][r] + bv;
    }
  }
}

// ---------- flash attention (causal), QBLK=128 (8 waves), KVBLK=64 ----------
// Swapped-QK^T; exp2-domain scores; fixed-reference softmax; l via ones-MFMA.
// T3/T4 pipeline: TRIPLE-buffered K/V (48 KB), prefetch depth 2, counted
// s_waitcnt vmcnt(2) + raw s_barrier (never drain to 0 mid-loop). Tile kt's
// loads are issued at step kt-2 -> ~2 steps to cover L3/HBM latency.
// qt128 blocks 8..15 split into two kv-chunks (bf16 partials + attn_combine).
// Grid (32,24) = 768 blocks, 3/CU (LDS 48KB, wave-cap 4).
__global__ __launch_bounds__(512) void flash_attn(
    const unsigned short* __restrict__ qk,
    const unsigned short* __restrict__ Vt,
    unsigned short* __restrict__ aout,
    unsigned short* __restrict__ Opart,  // [256][2][128][64] bf16
    float* __restrict__ Lpart) {         // [256][2][128]
  __shared__ __align__(16) unsigned short Ks[3][64 * 64];   // [k][d], swizzled
  __shared__ __align__(16) unsigned short Vs[3][64 * 64];   // [d][k], swizzled

  const int t = threadIdx.x, lane = t & 63, w = t >> 6;     // w: 0..7
  const int bh = blockIdx.x;
  const int yy = blockIdx.y;            // 0..23
  int qt, lo, hi, part = 0;
  bool split = false;
  if (yy < 8) {                         // whole blocks: qt 0..7
    qt = yy; lo = 0; hi = 2 * qt + 2;
  } else if (yy < 16) {                 // chunk part0 of qt 15..8
    qt = 15 - (yy - 8); part = 0; split = true;
    lo = 0; hi = qt + 1;
  } else {                              // chunk part1 of qt 15..8 (has diag)
    qt = 15 - (yy - 16); part = 1; split = true;
    lo = qt + 1; hi = 2 * qt + 2;
  }
  const int b = bh >> 4, h = bh & 15;
  const int lq = lane & 15;
  const int g  = lane >> 4;
  const int lk8 = g * 8;
  const int swzq = (lq & 7) << 3;
  const size_t basebs = (size_t)b * S_;
  const f32x4 z = {0.f, 0.f, 0.f, 0.f};
  const short8 ones = {(short)0x3F80, (short)0x3F80, (short)0x3F80,
                       (short)0x3F80, (short)0x3F80, (short)0x3F80,
                       (short)0x3F80, (short)0x3F80};   // bf16 1.0 x8

  // Q fragment: wave w owns q-rows qt*128 + w*16 + [0,16)
  short8 qf[2];
  {
    const int qrow = qt * 128 + w * 16 + lq;
    const unsigned short* qp = qk + (basebs + qrow) * QKS + h * HD_;
    qf[0] = *(const short8*)(qp + lk8);
    qf[1] = *(const short8*)(qp + 32 + lk8);
  }

  f32x4 l_acc = z;                      // l_acc[r] = l[q = 4g+r]
  f32x4 o_acc[4];
  #pragma unroll
  for (int n = 0; n < 4; ++n) o_acc[n] = z;

  // staging: 512 threads, 1 gload16 each for K and V per tile
  const int sr = t >> 3;                // 0..63
  const int scc = (t & 7) * 8;
  const unsigned short* kp =
      qk + (basebs + sr) * QKS + E_ + h * HD_ + (scc ^ ((sr & 7) << 3));
  const unsigned short* vp =
      Vt + ((size_t)bh * HD_ + sr) * S_ + (scc ^ ((sr & 7) << 3));

  auto stage = [&](int kt) {            // tile kt -> buffer kt%3
    const int buf = kt % 3;
    gload16(kp + (size_t)kt * 64 * QKS, &Ks[buf][t * 8]);
    gload16(vp + (size_t)kt * 64,       &Vs[buf][t * 8]);
  };

  // prologue: prefetch depth 2
  stage(lo);
  if (lo + 1 < hi) stage(lo + 1);

  for (int kt = lo; kt < hi; ++kt) {
    // counted wait: tile kt's 2 loads done; tile kt+1's may stay in flight
    if (kt < hi - 1) {
      asm volatile("s_waitcnt vmcnt(2)" ::: "memory");
    } else {
      asm volatile("s_waitcnt vmcnt(0)" ::: "memory");
    }
    __builtin_amdgcn_sched_barrier(0);
    __builtin_amdgcn_s_barrier();       // all waves' tile-kt loads landed;
    __builtin_amdgcn_sched_barrier(0);  // all waves done reading buf (kt-1)%3

    if (kt + 2 < hi) stage(kt + 2);     // overwrite buf (kt-1)%3 (now free)

    const int cur = kt % 3;
    const int krel = kt - 2 * qt;              // >=0 only on diag tiles
    const bool skip = (krel == 1) && (w < 4);  // fully-masked wave
    if (!skip) {
      f32x4 st[4];
      __builtin_amdgcn_s_setprio(1);
      #pragma unroll
      for (int f = 0; f < 4; ++f) {
        const int rowb = (f * 16 + lq) * 64;
        short8 kf0 = *(const short8*)&Ks[cur][rowb + (lk8 ^ swzq)];
        short8 kf1 = *(const short8*)&Ks[cur][rowb + ((lk8 + 32) ^ swzq)];
        st[f] = __builtin_amdgcn_mfma_f32_16x16x32_bf16(kf0, qf[0], z, 0, 0, 0);
        st[f] = __builtin_amdgcn_mfma_f32_16x16x32_bf16(kf1, qf[1], st[f], 0, 0, 0);
      }
      __builtin_amdgcn_s_setprio(0);

      if (krel >= 0) {                  // diagonal tile: causal mask
        const int qcol = w * 16 + lq;   // q pos within 128-block
        const int kbase = krel * 64;    // 0 or 64
        #pragma unroll
        for (int f = 0; f < 4; ++f)
          #pragma unroll
          for (int r = 0; r < 4; ++r)
            if (kbase + 16 * f + 4 * g + r > qcol) st[f][r] = -1e30f;
      }

      // P = exp2(S), packed bf16 pairs
      unsigned pw[4][2];
      #pragma unroll
      for (int f = 0; f < 4; ++f) {
        float p0 = exp2_fast(st[f][0]);
        float p1 = exp2_fast(st[f][1]);
        float p2 = exp2_fast(st[f][2]);
        float p3 = exp2_fast(st[f][3]);
        asm("v_cvt_pk_bf16_f32 %0, %1, %2" : "=v"(pw[f][0]) : "v"(p0), "v"(p1));
        asm("v_cvt_pk_bf16_f32 %0, %1, %2" : "=v"(pw[f][1]) : "v"(p2), "v"(p3));
      }

      // in-register P redistribution: permlane32_swap + permlane16_swap chains
      unsigned c1a = pw[0][0], c1b = pw[1][0];
      unsigned c2a = pw[0][1], c2b = pw[1][1];
      unsigned c3a = pw[2][0], c3b = pw[3][0];
      unsigned c4a = pw[2][1], c4b = pw[3][1];
      asm("v_permlane32_swap_b32 %0, %1" : "+v"(c1a), "+v"(c1b));
      asm("v_permlane16_swap_b32 %0, %1" : "+v"(c1a), "+v"(c1b));
      asm("v_permlane32_swap_b32 %0, %1" : "+v"(c2a), "+v"(c2b));
      asm("v_permlane16_swap_b32 %0, %1" : "+v"(c2a), "+v"(c2b));
      asm("v_permlane32_swap_b32 %0, %1" : "+v"(c3a), "+v"(c3b));
      asm("v_permlane16_swap_b32 %0, %1" : "+v"(c3a), "+v"(c3b));
      asm("v_permlane32_swap_b32 %0, %1" : "+v"(c4a), "+v"(c4b));
      asm("v_permlane16_swap_b32 %0, %1" : "+v"(c4a), "+v"(c4b));
      union U8 { unsigned u[4]; short8 s; };
      U8 pa0u = {{c1a, c2a, c1b, c2b}};
      U8 pa1u = {{c3a, c4a, c3b, c4b}};
      const short8 pa0 = pa0u.s, pa1 = pa1u.s;

      __builtin_amdgcn_s_setprio(1);
      #pragma unroll
      for (int n = 0; n < 4; ++n) {
        const int rowb = (n * 16 + lq) * 64;
        short8 vb0 = *(const short8*)&Vs[cur][rowb + (lk8 ^ swzq)];
        short8 vb1 = *(const short8*)&Vs[cur][rowb + ((lk8 + 32) ^ swzq)];
        o_acc[n] = __builtin_amdgcn_mfma_f32_16x16x32_bf16(pa0, vb0, o_acc[n], 0, 0, 0);
        o_acc[n] = __builtin_amdgcn_mfma_f32_16x16x32_bf16(pa1, vb1, o_acc[n], 0, 0, 0);
      }
      // denominator: row-sum of P via constant-ones B operand
      l_acc = __builtin_amdgcn_mfma_f32_16x16x32_bf16(pa0, ones, l_acc, 0, 0, 0);
      l_acc = __builtin_amdgcn_mfma_f32_16x16x32_bf16(pa1, ones, l_acc, 0, 0, 0);
      __builtin_amdgcn_s_setprio(0);
    }
    __builtin_amdgcn_sched_barrier(0);  // keep compute inside its step
  }

  if (!split) {
    const int qbase = qt * 128 + w * 16 + 4 * g;
    #pragma unroll
    for (int r = 0; r < 4; ++r) {
      const float inv = 1.0f / l_acc[r];
      const int row = qbase + r;
      #pragma unroll
      for (int n = 0; n < 4; ++n)
        aout[(basebs + row) * E_ + h * HD_ + n * 16 + lq] =
            f2bf(o_acc[n][r] * inv);
    }
  } else {
    // bf16 unnormalized partials; slot owned exclusively by this chunk
    const int sidx = (bh << 3) | (qt - 8);
    unsigned short* Ob = Opart + ((size_t)(sidx * 2 + part) << 13);  // 128*64
    #pragma unroll
    for (int r = 0; r < 4; ++r) {
      const int qrow = w * 16 + 4 * g + r;
      #pragma unroll
      for (int n = 0; n < 4; ++n)
        Ob[qrow * 64 + n * 16 + lq] = f2bf(o_acc[n][r]);
    }
    if (lq == 0) {
      #pragma unroll
      for (int r = 0; r < 4; ++r)
        Lpart[(sidx * 2 + part) * 128 + w * 16 + 4 * g + r] = l_acc[r];
    }
  }
}

// ---------------- combine partials for split row-blocks ----------------
__global__ __launch_bounds__(256) void attn_combine(
    const unsigned short* __restrict__ Opart, const float* __restrict__ Lpart,
    unsigned short* __restrict__ aout) {
  const int s = blockIdx.x;            // 0..255
  const int bh = s >> 3, qtb = 8 + (s & 7);
  const int b = bh >> 4, h = bh & 15;
  const int t = threadIdx.x;
  const int q = t >> 1;                // 0..127
  const int d0 = (t & 1) * 32;
  const float l = Lpart[(s * 2 + 0) * 128 + q] + Lpart[(s * 2 + 1) * 128 + q];
  const float inv = 1.0f / l;
  const unsigned short* p0 = Opart + ((size_t)(s * 2 + 0) << 13) + q * 64 + d0;
  const unsigned short* p1 = Opart + ((size_t)(s * 2 + 1) << 13) + q * 64 + d0;
  unsigned short* dst =
      aout + ((size_t)b * S_ + qtb * 128 + q) * E_ + h * HD_ + d0;
  #pragma unroll
  for (int i = 0; i < 32; ++i)
    dst[i] = f2bf((bf2f(p0[i]) + bf2f(p1[i])) * inv);
}

extern "C" void kernel_launch(void* const* d_in, const int* in_sizes, int n_in,
                              void* d_out, int out_size, void* d_ws, size_t ws_size,
                              hipStream_t stream) {
  const float* X  = (const float*)d_in[0];
  const float* Wa = (const float*)d_in[1];
  const float* ba = (const float*)d_in[2];
  const float* Wp = (const float*)d_in[3];
  const float* bp = (const float*)d_in[4];
  float* out = (float*)d_out;

  char* ws = (char*)d_ws;
  unsigned short* Xb  = (unsigned short*)ws; ws += (size_t)M_ * E_ * 2;    // 8 MB
  unsigned short* WaT = (unsigned short*)ws; ws += (size_t)E3_ * E_ * 2;   // 6 MB
  unsigned short* WpT = (unsigned short*)ws; ws += (size_t)E_ * E_ * 2;    // 2 MB
  unsigned short* QK  = (unsigned short*)ws; ws += (size_t)M_ * QKS * 2;   // 16 MB
  unsigned short* Vt  = (unsigned short*)ws; ws += (size_t)M_ * E_ * 2;    // 8 MB
  unsigned short* AO  = (unsigned short*)ws; ws += (size_t)M_ * E_ * 2;    // 8 MB
  unsigned short* Opart = (unsigned short*)ws;
  ws += (size_t)256 * 2 * 128 * 64 * 2;                                    // 8.4 MB
  float* Lpart = (float*)ws; ws += (size_t)256 * 2 * 128 * 4;              // 256 KB

  prep<<<8192, 256, 0, stream>>>(X, Wa, Wp, Xb, WaT, WpT);
  gemm_bt_bias<1><<<dim3(E3_ / 128, M_ / 128), 256, 0, stream>>>(
      Xb, WaT, ba, nullptr, QK, Vt, M_, E3_, E_);
  flash_attn<<<dim3(B_ * H_, 24), 512, 0, stream>>>(QK, Vt, AO, Opart, Lpart);
  attn_combine<<<256, 256, 0, stream>>>(Opart, Lpart, AO);
  gemm_proj<<<dim3(E_ / 64, M_ / 128), 256, 0, stream>>>(
      AO, WpT, bp, out, M_, E_, E_);
}